// Round 13
// baseline (1421.743 us; speedup 1.0000x reference)
//
#include <hip/hip_runtime.h>

#define HH 512
#define WW 512
#define NC 25              // final channel count: 1 + 12*2
#define HWs (HH * WW)

__device__ __forceinline__ int refl(int p, int n) {
    p = (p < 0) ? -p : p;
    p = (p >= n) ? (2 * n - 2 - p) : p;
    return p;
}

// R13: R8's proven structure (331.9us) with the slow tail CLASS removed.
// Overlap tiling: M6 = ceil(512/6d) row-base groups; the last group's base
// clamps to 512-6d, recomputing 3-12.5% of rows with bitwise-identical
// values (no channel rotation -> same summation order -> duplicate
// concurrent writes of identical dwords, benign). Every block runs the fast
// 6-row dilation-symmetry path (24 loads / 6px / channel); the old tail
// fallback (36 loads/channel, 1.5x block critical path on DIL=9..11 layers,
// where each dispatch = ONE block-generation = max block time) is gone.
// Layer 0 fuses the x->channel0 copy (epilogue writes its 6 rows from the
// already-loaded center taps) -> one fewer dispatch.
// Ping-pong depth-1 (deeper refuted R10/R12), (256,3)=85-VGPR cap (fits,
// R5 lesson: tighter caps spill), XCD swizzle, 12 dispatches total.
template <int NIN, int DIL, bool FC>
__global__ __launch_bounds__(256, 3) void msd_layer(const float* __restrict__ wts,
                                                    const float* __restrict__ bias,
                                                    float* __restrict__ buf,
                                                    const float* __restrict__ xsrc,
                                                    int layer) {
    static_assert(!FC || NIN == 1, "copy fusion only for layer 0");
    constexpr int M6 = (512 + 6 * DIL - 1) / (6 * DIL);   // ceil: overlap tiling
    constexpr int DM = DIL * M6;          // row-bases per image
    constexpr int IMT = 512 * DM;         // threads per image
    // grid is exactly 4*IMT/256 = 8*DM blocks; no tail path exists

    // ---- bijective chunked XCD swizzle (MI355X: 8 XCDs, round-robin) ----
    int bid = blockIdx.x;
    {
        const int nblk = gridDim.x;
        const int q = nblk >> 3, r = nblk & 7;
        const int xcd = bid & 7, idx = bid >> 3;
        bid = (xcd < r ? xcd * (q + 1) : r * (q + 1) + (xcd - r) * q) + idx;
    }
    const int t = bid * 256 + threadIdx.x;

    const float b0 = bias[2 * layer];
    const float b1 = bias[2 * layer + 1];

    const int img = t / IMT;                       // uniform per block
    const int u = t - img * IMT;
    const int bi = __builtin_amdgcn_readfirstlane(u >> 9);   // base index
    const int w = u & 511;                         // per-lane column
    const int k = bi / DIL, j = bi - k * DIL;
    int hb = 6 * DIL * k;                          // group base (scalar)
    if (hb > 512 - 6 * DIL) hb = 512 - 6 * DIL;    // overlap clamp (last group)
    const int h = hb + j;                          // base output row (scalar)

    int rowoff[8];                                 // rows h+(r-1)*d, scalar
#pragma unroll
    for (int r = 0; r < 8; ++r) rowoff[r] = refl(h + (r - 1) * DIL, HH) * WW;
    int cw[3];                                     // per-lane col taps
#pragma unroll
    for (int q = 0; q < 3; ++q) cw[q] = refl(w + (q - 1) * DIL, WW);

    float a0[6], a1[6];
#pragma unroll
    for (int al = 0; al < 6; ++al) { a0[al] = b0; a1[al] = b1; }
    const float* base = buf + (size_t)img * NC * HWs;

    float vA[8][3], vB[8][3];

    auto LD = [&](float (&v)[8][3], int c) {
        const float* plane = (FC && c == 0) ? (xsrc + (size_t)img * HWs)
                                            : (base + (size_t)c * HWs);
#pragma unroll
        for (int r = 0; r < 8; ++r) {
            const float* rowp = plane + rowoff[r];
#pragma unroll
            for (int q = 0; q < 3; ++q) v[r][q] = rowp[cw[q]];
        }
    };
    auto FM = [&](const float (&v)[8][3], int c) {
        float wk0[9], wk1[9];
#pragma unroll
        for (int kk = 0; kk < 9; ++kk) {
            wk0[kk] = wts[c * 9 + kk];             // uniform -> s_load
            wk1[kk] = wts[(NIN + c) * 9 + kk];
        }
#pragma unroll
        for (int al = 0; al < 6; ++al)
#pragma unroll
            for (int kr = 0; kr < 3; ++kr)
#pragma unroll
                for (int kw = 0; kw < 3; ++kw) {
                    float vv = v[al + kr][kw];
                    a0[al] = fmaf(vv, wk0[kr * 3 + kw], a0[al]);
                    a1[al] = fmaf(vv, wk1[kr * 3 + kw], a1[al]);
                }
    };

    LD(vA, 0);
#pragma unroll
    for (int i = 0; i < NIN; i += 2) {
        if (i + 1 < NIN) LD(vB, i + 1);            // issue B loads
        FM(vA, i);                                 // compute A
        if (i + 1 >= NIN) break;
        if (i + 2 < NIN) LD(vA, i + 2);            // issue A loads
        FM(vB, i + 1);                             // compute B
    }

    if (FC) {                                      // fused x -> channel 0 copy
        float* oc = buf + (size_t)img * NC * HWs;  // channel 0 plane
#pragma unroll
        for (int al = 0; al < 6; ++al)
            oc[(size_t)(h + al * DIL) * WW + (size_t)w] = vA[al + 1][1];
    }

    float* o0 = buf + (size_t)(img * NC + NIN) * HWs;
    float* o1 = o0 + HWs;
#pragma unroll
    for (int al = 0; al < 6; ++al) {
        size_t off = (size_t)(h + al * DIL) * WW + (size_t)w;
        o0[off] = fmaxf(a0[al], 0.f);
        o1[off] = fmaxf(a1[al], 0.f);
    }
}

extern "C" void kernel_launch(void* const* d_in, const int* in_sizes, int n_in,
                              void* d_out, int out_size, void* d_ws, size_t ws_size,
                              hipStream_t stream) {
    const float* x = (const float*)d_in[0];
    const float* bias = (const float*)d_in[1];
    float* out = (float*)d_out;

// overlap tiling: blocks = 8 * DIL * ceil(512/(6*DIL)); no tail blocks
#define GBLK(dil) (8 * (dil) * ((512 + 6 * (dil) - 1) / (6 * (dil))))
#define LAYER(i, nin, dil, fc, xp) \
    msd_layer<nin, dil, fc><<<GBLK(dil), 256, 0, stream>>>( \
        (const float*)d_in[2 + i], bias, out, xp, i)

    LAYER(0, 1, 1, true, x);          // fuses x -> channel 0 copy
    LAYER(1, 3, 2, false, nullptr);
    LAYER(2, 5, 3, false, nullptr);
    LAYER(3, 7, 4, false, nullptr);
    LAYER(4, 9, 5, false, nullptr);
    LAYER(5, 11, 6, false, nullptr);
    LAYER(6, 13, 7, false, nullptr);
    LAYER(7, 15, 8, false, nullptr);
    LAYER(8, 17, 9, false, nullptr);
    LAYER(9, 19, 10, false, nullptr);
    LAYER(10, 21, 11, false, nullptr);
    LAYER(11, 23, 12, false, nullptr);
#undef LAYER
#undef GBLK
}

// Round 14
// 531.241 us; speedup vs baseline: 2.6763x; 2.6763x over previous
//
#include <hip/hip_runtime.h>

#define HH 512
#define WW 512
#define NC 25              // final channel count: 1 + 12*2
#define HWs (HH * WW)

__device__ __forceinline__ int refl(int p, int n) {
    p = (p < 0) ? -p : p;
    p = (p >= n) ? (2 * n - 2 - p) : p;
    return p;
}

__global__ __launch_bounds__(256) void copy_x_kernel(const float* __restrict__ x,
                                                     float* __restrict__ out) {
    int t = blockIdx.x * 256 + threadIdx.x;   // NB*HWs/4 = 262144 threads
    int b = t >> 16;                          // HWs/4 = 65536 float4 per batch
    int r = t & 65535;
    const float4* src = (const float4*)(x + (size_t)b * HWs);
    float4* dst = (float4*)(out + (size_t)b * NC * HWs);
    dst[r] = src[r];
}

// FINAL (R14 = exact R8 revert, best measured 331.9us):
// 6-row dilation-symmetry scheme — thread owns rows h+al*DIL (al=0..5, one
// column); the 8 loaded rows {h-d..h+6d} x 3 col-taps serve all 54 row-taps:
// 24 dword loads / 6 px / channel (halo factor 1.33 vs 1.67 at 3-row).
// Lane = consecutive col -> dense 256B wave-loads; row bases scalar
// (readfirstlane). Ping-pong A/B channel buffers (depth-1; deeper prefetch
// refuted twice: R10/R12). Per-block channel rotation + bijective XCD
// swizzle. (256,3) = 85-VGPR cap: the ONLY cap at which the full ping-pong
// live set fits without spill (R5: 32-cap spills catastrophically; R13:
// structural perturbation at this cap spills too — do not restructure).
// Session evidence: kernel is TA-request-rate + dependency-stall bound;
// occupancy (R6), stagger (R7), LDS (R2), fusion (R4), depth (R10/R12),
// widening (R11), tail-removal (R13) all falsified. Request reduction
// (R8: -20% req -> -8.5% time) is the one validated lever, exhausted at
// this halo factor.
template <int NIN, int DIL>
__global__ __launch_bounds__(256, 3) void msd_layer(const float* __restrict__ wts,
                                                    const float* __restrict__ bias,
                                                    float* __restrict__ buf,
                                                    int layer) {
    constexpr int M6 = 512 / (6 * DIL);
    constexpr int DM = DIL * M6;          // row-bases per image
    constexpr int SPAN = 6 * DM;          // rows covered by main path
    constexpr int RT = 512 - SPAN;        // tail rows (0..50)
    constexpr int TCH = (RT + 3) / 4;     // tail chunks of 4 rows
    constexpr int IMT = 512 * DM;         // main threads per image
    constexpr int NMAIN = 4 * IMT;

    int bid = blockIdx.x;
    {
        const int nblk = gridDim.x;
        const int q = nblk >> 3, r = nblk & 7;
        const int xcd = bid & 7, idx = bid >> 3;
        bid = (xcd < r ? xcd * (q + 1) : r * (q + 1) + (xcd - r) * q) + idx;
    }
    const int t = bid * 256 + threadIdx.x;

    const float b0 = bias[2 * layer];
    const float b1 = bias[2 * layer + 1];

    if (t < NMAIN) {
        const int img = t / IMT;                       // uniform per block
        const int u = t - img * IMT;
        const int bi = __builtin_amdgcn_readfirstlane(u >> 9);   // base index
        const int w = u & 511;                         // per-lane column
        const int k = bi / DIL, j = bi - k * DIL;
        const int h = 6 * DIL * k + j;                 // base output row (scalar)

        int rowoff[8];
#pragma unroll
        for (int r = 0; r < 8; ++r) rowoff[r] = refl(h + (r - 1) * DIL, HH) * WW;
        int cw[3];
#pragma unroll
        for (int q = 0; q < 3; ++q) cw[q] = refl(w + (q - 1) * DIL, WW);

        float a0[6], a1[6];
#pragma unroll
        for (int al = 0; al < 6; ++al) { a0[al] = b0; a1[al] = b1; }
        const float* base = buf + (size_t)img * NC * HWs;

        const int c0 = bid - (bid / NIN) * NIN;        // bid % NIN (rotation)

        float vA[8][3], vB[8][3];

        auto LD = [&](float (&v)[8][3], int c) {
            const float* plane = base + (size_t)c * HWs;
#pragma unroll
            for (int r = 0; r < 8; ++r) {
                const float* rowp = plane + rowoff[r];
#pragma unroll
                for (int q = 0; q < 3; ++q) v[r][q] = rowp[cw[q]];
            }
        };
        auto FM = [&](const float (&v)[8][3], int c) {
            float wk0[9], wk1[9];
#pragma unroll
            for (int kk = 0; kk < 9; ++kk) {
                wk0[kk] = wts[c * 9 + kk];             // uniform -> s_load
                wk1[kk] = wts[(NIN + c) * 9 + kk];
            }
#pragma unroll
            for (int al = 0; al < 6; ++al)
#pragma unroll
                for (int kr = 0; kr < 3; ++kr)
#pragma unroll
                    for (int kw = 0; kw < 3; ++kw) {
                        float vv = v[al + kr][kw];
                        a0[al] = fmaf(vv, wk0[kr * 3 + kw], a0[al]);
                        a1[al] = fmaf(vv, wk1[kr * 3 + kw], a1[al]);
                    }
        };

        LD(vA, c0);
#pragma unroll
        for (int i = 0; i < NIN; i += 2) {
            int cA = c0 + i;     cA -= (cA >= NIN) ? NIN : 0;
            int cB = c0 + i + 1; cB -= (cB >= NIN) ? NIN : 0;
            if (i + 1 < NIN) LD(vB, cB);
            FM(vA, cA);
            if (i + 1 >= NIN) break;
            int cN = c0 + i + 2; cN -= (cN >= NIN) ? NIN : 0;
            if (i + 2 < NIN) LD(vA, cN);
            FM(vB, cB);
        }

        float* o0 = buf + (size_t)(img * NC + NIN) * HWs;
        float* o1 = o0 + HWs;
#pragma unroll
        for (int al = 0; al < 6; ++al) {
            size_t off = (size_t)(h + al * DIL) * WW + (size_t)w;
            o0[off] = fmaxf(a0[al], 0.f);
            o1[off] = fmaxf(a1[al], 0.f);
        }
    } else if (RT > 0) {
        const int t2 = t - NMAIN;
        constexpr int PIT = 512 * TCH;
        const int img = t2 / PIT;
        const int u = t2 - img * PIT;
        const int s = __builtin_amdgcn_readfirstlane(u >> 9);
        const int w = u & 511;
        const int r0 = SPAN + 4 * s;

        int cw[3];
#pragma unroll
        for (int q = 0; q < 3; ++q) cw[q] = refl(w + (q - 1) * DIL, WW);
        int ro[3][4];
#pragma unroll
        for (int kr = 0; kr < 3; ++kr)
#pragma unroll
            for (int i = 0; i < 4; ++i)
                ro[kr][i] = refl(r0 + i + (kr - 1) * DIL, HH) * WW;

        float a0[4] = {b0, b0, b0, b0};
        float a1[4] = {b1, b1, b1, b1};
        const float* base = buf + (size_t)img * NC * HWs;

        for (int c = 0; c < NIN; ++c) {
            const float* plane = base + (size_t)c * HWs;
            float wk0[9], wk1[9];
#pragma unroll
            for (int kk = 0; kk < 9; ++kk) {
                wk0[kk] = wts[c * 9 + kk];
                wk1[kk] = wts[(NIN + c) * 9 + kk];
            }
#pragma unroll
            for (int i = 0; i < 4; ++i) {
                if (r0 + i < HH) {
#pragma unroll
                    for (int kr = 0; kr < 3; ++kr) {
                        const float* rowp = plane + ro[kr][i];
#pragma unroll
                        for (int kw = 0; kw < 3; ++kw) {
                            float vv = rowp[cw[kw]];
                            a0[i] = fmaf(vv, wk0[kr * 3 + kw], a0[i]);
                            a1[i] = fmaf(vv, wk1[kr * 3 + kw], a1[i]);
                        }
                    }
                }
            }
        }

        float* o0 = buf + (size_t)(img * NC + NIN) * HWs;
        float* o1 = o0 + HWs;
#pragma unroll
        for (int i = 0; i < 4; ++i) {
            if (r0 + i < HH) {
                size_t off = (size_t)(r0 + i) * WW + (size_t)w;
                o0[off] = fmaxf(a0[i], 0.f);
                o1[off] = fmaxf(a1[i], 0.f);
            }
        }
    }
}

extern "C" void kernel_launch(void* const* d_in, const int* in_sizes, int n_in,
                              void* d_out, int out_size, void* d_ws, size_t ws_size,
                              hipStream_t stream) {
    const float* x = (const float*)d_in[0];
    const float* bias = (const float*)d_in[1];
    float* out = (float*)d_out;

    copy_x_kernel<<<1024, 256, 0, stream>>>(x, out);

// blocks = (main + tail threads)/256 = 8*DM + 8*TCH  (6-row scheme)
#define GBLK(dil) (8 * ((dil) * (512 / (6 * (dil)))) \
                 + 8 * (((512 - 6 * ((dil) * (512 / (6 * (dil))))) + 3) / 4))
#define LAYER(i, nin, dil) \
    msd_layer<nin, dil><<<GBLK(dil), 256, 0, stream>>>((const float*)d_in[2 + i], bias, out, i)

    LAYER(0, 1, 1);
    LAYER(1, 3, 2);
    LAYER(2, 5, 3);
    LAYER(3, 7, 4);
    LAYER(4, 9, 5);
    LAYER(5, 11, 6);
    LAYER(6, 13, 7);
    LAYER(7, 15, 8);
    LAYER(8, 17, 9);
    LAYER(9, 19, 10);
    LAYER(10, 21, 11);
    LAYER(11, 23, 12);
#undef LAYER
#undef GBLK
}

// Round 15
// 334.078 us; speedup vs baseline: 4.2557x; 1.5902x over previous
//
#include <hip/hip_runtime.h>

#define HH 512
#define WW 512
#define NC 25              // final channel count: 1 + 12*2
#define HWs (HH * WW)

__device__ __forceinline__ int refl(int p, int n) {
    p = (p < 0) ? -p : p;
    p = (p >= n) ? (2 * n - 2 - p) : p;
    return p;
}

__global__ __launch_bounds__(256) void copy_x_kernel(const float* __restrict__ x,
                                                     float* __restrict__ out) {
    int t = blockIdx.x * 256 + threadIdx.x;   // NB*HWs/4 = 262144 threads
    int b = t >> 16;                          // HWs/4 = 65536 float4 per batch
    int r = t & 65535;
    const float4* src = (const float4*)(x + (size_t)b * HWs);
    float4* dst = (float4*)(out + (size_t)b * NC * HWs);
    dst[r] = src[r];
}

// R15: REPLICATION PROBE. R14 (byte-identical to R8) measured 531.2us vs
// R8's 331.9us — 60% swing on unchanged code, while harness fills stayed
// at 62-64us in every run and no msd_layer dispatch exceeded ~62us in
// either profile pass (per-dispatch kernel time NOT 60% slower; inflation
// is in the timed pass / inter-dispatch gaps). Two prior consistent
// measurements of this structure (R8 = 331.9; R9 layers ~= 332 by counter
// reconciliation; R12 fences-variant = 338.9) vs one at 531. Re-measuring
// identical code to classify: outlier | environment-shift | high-variance.
// Kernel = R8 verbatim: 6-row dilation-symmetry scheme (24 loads / 6 px /
// channel), ping-pong depth-1, channel rotation, XCD swizzle, (256,3).
template <int NIN, int DIL>
__global__ __launch_bounds__(256, 3) void msd_layer(const float* __restrict__ wts,
                                                    const float* __restrict__ bias,
                                                    float* __restrict__ buf,
                                                    int layer) {
    constexpr int M6 = 512 / (6 * DIL);
    constexpr int DM = DIL * M6;          // row-bases per image
    constexpr int SPAN = 6 * DM;          // rows covered by main path
    constexpr int RT = 512 - SPAN;        // tail rows (0..50)
    constexpr int TCH = (RT + 3) / 4;     // tail chunks of 4 rows
    constexpr int IMT = 512 * DM;         // main threads per image
    constexpr int NMAIN = 4 * IMT;

    int bid = blockIdx.x;
    {
        const int nblk = gridDim.x;
        const int q = nblk >> 3, r = nblk & 7;
        const int xcd = bid & 7, idx = bid >> 3;
        bid = (xcd < r ? xcd * (q + 1) : r * (q + 1) + (xcd - r) * q) + idx;
    }
    const int t = bid * 256 + threadIdx.x;

    const float b0 = bias[2 * layer];
    const float b1 = bias[2 * layer + 1];

    if (t < NMAIN) {
        const int img = t / IMT;                       // uniform per block
        const int u = t - img * IMT;
        const int bi = __builtin_amdgcn_readfirstlane(u >> 9);   // base index
        const int w = u & 511;                         // per-lane column
        const int k = bi / DIL, j = bi - k * DIL;
        const int h = 6 * DIL * k + j;                 // base output row (scalar)

        int rowoff[8];
#pragma unroll
        for (int r = 0; r < 8; ++r) rowoff[r] = refl(h + (r - 1) * DIL, HH) * WW;
        int cw[3];
#pragma unroll
        for (int q = 0; q < 3; ++q) cw[q] = refl(w + (q - 1) * DIL, WW);

        float a0[6], a1[6];
#pragma unroll
        for (int al = 0; al < 6; ++al) { a0[al] = b0; a1[al] = b1; }
        const float* base = buf + (size_t)img * NC * HWs;

        const int c0 = bid - (bid / NIN) * NIN;        // bid % NIN (rotation)

        float vA[8][3], vB[8][3];

        auto LD = [&](float (&v)[8][3], int c) {
            const float* plane = base + (size_t)c * HWs;
#pragma unroll
            for (int r = 0; r < 8; ++r) {
                const float* rowp = plane + rowoff[r];
#pragma unroll
                for (int q = 0; q < 3; ++q) v[r][q] = rowp[cw[q]];
            }
        };
        auto FM = [&](const float (&v)[8][3], int c) {
            float wk0[9], wk1[9];
#pragma unroll
            for (int kk = 0; kk < 9; ++kk) {
                wk0[kk] = wts[c * 9 + kk];             // uniform -> s_load
                wk1[kk] = wts[(NIN + c) * 9 + kk];
            }
#pragma unroll
            for (int al = 0; al < 6; ++al)
#pragma unroll
                for (int kr = 0; kr < 3; ++kr)
#pragma unroll
                    for (int kw = 0; kw < 3; ++kw) {
                        float vv = v[al + kr][kw];
                        a0[al] = fmaf(vv, wk0[kr * 3 + kw], a0[al]);
                        a1[al] = fmaf(vv, wk1[kr * 3 + kw], a1[al]);
                    }
        };

        LD(vA, c0);
#pragma unroll
        for (int i = 0; i < NIN; i += 2) {
            int cA = c0 + i;     cA -= (cA >= NIN) ? NIN : 0;
            int cB = c0 + i + 1; cB -= (cB >= NIN) ? NIN : 0;
            if (i + 1 < NIN) LD(vB, cB);
            FM(vA, cA);
            if (i + 1 >= NIN) break;
            int cN = c0 + i + 2; cN -= (cN >= NIN) ? NIN : 0;
            if (i + 2 < NIN) LD(vA, cN);
            FM(vB, cB);
        }

        float* o0 = buf + (size_t)(img * NC + NIN) * HWs;
        float* o1 = o0 + HWs;
#pragma unroll
        for (int al = 0; al < 6; ++al) {
            size_t off = (size_t)(h + al * DIL) * WW + (size_t)w;
            o0[off] = fmaxf(a0[al], 0.f);
            o1[off] = fmaxf(a1[al], 0.f);
        }
    } else if (RT > 0) {
        const int t2 = t - NMAIN;
        constexpr int PIT = 512 * TCH;
        const int img = t2 / PIT;
        const int u = t2 - img * PIT;
        const int s = __builtin_amdgcn_readfirstlane(u >> 9);
        const int w = u & 511;
        const int r0 = SPAN + 4 * s;

        int cw[3];
#pragma unroll
        for (int q = 0; q < 3; ++q) cw[q] = refl(w + (q - 1) * DIL, WW);
        int ro[3][4];
#pragma unroll
        for (int kr = 0; kr < 3; ++kr)
#pragma unroll
            for (int i = 0; i < 4; ++i)
                ro[kr][i] = refl(r0 + i + (kr - 1) * DIL, HH) * WW;

        float a0[4] = {b0, b0, b0, b0};
        float a1[4] = {b1, b1, b1, b1};
        const float* base = buf + (size_t)img * NC * HWs;

        for (int c = 0; c < NIN; ++c) {
            const float* plane = base + (size_t)c * HWs;
            float wk0[9], wk1[9];
#pragma unroll
            for (int kk = 0; kk < 9; ++kk) {
                wk0[kk] = wts[c * 9 + kk];
                wk1[kk] = wts[(NIN + c) * 9 + kk];
            }
#pragma unroll
            for (int i = 0; i < 4; ++i) {
                if (r0 + i < HH) {
#pragma unroll
                    for (int kr = 0; kr < 3; ++kr) {
                        const float* rowp = plane + ro[kr][i];
#pragma unroll
                        for (int kw = 0; kw < 3; ++kw) {
                            float vv = rowp[cw[kw]];
                            a0[i] = fmaf(vv, wk0[kr * 3 + kw], a0[i]);
                            a1[i] = fmaf(vv, wk1[kr * 3 + kw], a1[i]);
                        }
                    }
                }
            }
        }

        float* o0 = buf + (size_t)(img * NC + NIN) * HWs;
        float* o1 = o0 + HWs;
#pragma unroll
        for (int i = 0; i < 4; ++i) {
            if (r0 + i < HH) {
                size_t off = (size_t)(r0 + i) * WW + (size_t)w;
                o0[off] = fmaxf(a0[i], 0.f);
                o1[off] = fmaxf(a1[i], 0.f);
            }
        }
    }
}

extern "C" void kernel_launch(void* const* d_in, const int* in_sizes, int n_in,
                              void* d_out, int out_size, void* d_ws, size_t ws_size,
                              hipStream_t stream) {
    const float* x = (const float*)d_in[0];
    const float* bias = (const float*)d_in[1];
    float* out = (float*)d_out;

    copy_x_kernel<<<1024, 256, 0, stream>>>(x, out);

// blocks = (main + tail threads)/256 = 8*DM + 8*TCH  (6-row scheme)
#define GBLK(dil) (8 * ((dil) * (512 / (6 * (dil)))) \
                 + 8 * (((512 - 6 * ((dil) * (512 / (6 * (dil))))) + 3) / 4))
#define LAYER(i, nin, dil) \
    msd_layer<nin, dil><<<GBLK(dil), 256, 0, stream>>>((const float*)d_in[2 + i], bias, out, i)

    LAYER(0, 1, 1);
    LAYER(1, 3, 2);
    LAYER(2, 5, 3);
    LAYER(3, 7, 4);
    LAYER(4, 9, 5);
    LAYER(5, 11, 6);
    LAYER(6, 13, 7);
    LAYER(7, 15, 8);
    LAYER(8, 17, 9);
    LAYER(9, 19, 10);
    LAYER(10, 21, 11);
    LAYER(11, 23, 12);
#undef LAYER
#undef GBLK
}